// Round 13
// baseline (176.136 us; speedup 1.0000x reference)
//
#include <hip/hip_runtime.h>

#define S_LEN 2048
#define D_DIM 64
#define BH_N  32
#define QT    64
#define NQT   (S_LEN / QT)   // 32
#define SWZ(r) (((r) & 7) << 4)

typedef short bf16x8 __attribute__((ext_vector_type(8)));
typedef float f32x4  __attribute__((ext_vector_type(4)));
typedef unsigned short u16;
typedef unsigned int   u32;

static __device__ __forceinline__ u16 f2bf(float x) {
    unsigned u = __float_as_uint(x);
    u += 0x7fffu + ((u >> 16) & 1u);          // RNE
    return (u16)(u >> 16);
}
static __device__ __forceinline__ u32 pack2(float a, float b) {
    return (u32)f2bf(a) | ((u32)f2bf(b) << 16);
}

#define MFMA(a, b, acc) __builtin_amdgcn_mfma_f32_16x16x32_bf16((a), (b), (acc), 0, 0, 0)

// ===================== prep: bf16 K/V tile-images (round-6-verified) =====================
//   Kimg byte(k,d) = k*128 + ((2d) ^ SWZ(k))   (row-major, swizzled)
//   Vimg byte(d,k) = d*128 + ((2k) ^ SWZ(d))   (transposed, swizzled)
__global__ __launch_bounds__(256)
void build_imgs(const float* __restrict__ K, const float* __restrict__ V,
                u16* __restrict__ Kimg, u16* __restrict__ Vimg)
{
    const int blk = blockIdx.x;               // bh*32 + kt
    const int tid = threadIdx.x;
    const float* Ksrc = K + (size_t)blk * 4096;
    const float* Vsrc = V + (size_t)blk * 4096;
    char* Kt = (char*)(Kimg + (size_t)blk * 4096);
    char* Vt = (char*)(Vimg + (size_t)blk * 4096);
    {   // K: thread covers row kr, 16 cols from kcb
        int kr = tid >> 2, kcb = (tid & 3) * 16;
        const float* p = Ksrc + kr * 64 + kcb;
        float4 a = ((const float4*)p)[0], b = ((const float4*)p)[1];
        float4 e = ((const float4*)p)[2], d = ((const float4*)p)[3];
        u32 t[8] = {pack2(a.x,a.y), pack2(a.z,a.w), pack2(b.x,b.y), pack2(b.z,b.w),
                    pack2(e.x,e.y), pack2(e.z,e.w), pack2(d.x,d.y), pack2(d.z,d.w)};
        char* dst = Kt + kr * 128;
        *(uint4*)(dst + ((2*kcb)      ^ SWZ(kr))) = ((uint4*)t)[0];
        *(uint4*)(dst + ((2*kcb + 16) ^ SWZ(kr))) = ((uint4*)t)[1];
    }
    {   // V: thread covers k-pair vk2, d-octet vdh; writes transposed
        int vk2 = (tid & 31) * 2, vdh = tid >> 5;
        const float* p0 = Vsrc + vk2 * 64 + vdh * 8;
        const float* p1 = p0 + 64;
        float4 a0 = ((const float4*)p0)[0], b0 = ((const float4*)p0)[1];
        float4 a1 = ((const float4*)p1)[0], b1 = ((const float4*)p1)[1];
        float e0[8] = {a0.x,a0.y,a0.z,a0.w,b0.x,b0.y,b0.z,b0.w};
        float e1[8] = {a1.x,a1.y,a1.z,a1.w,b1.x,b1.y,b1.z,b1.w};
        #pragma unroll
        for (int i = 0; i < 8; ++i) {
            int d = vdh * 8 + i;
            *(u32*)(Vt + d * 128 + ((2 * vk2) ^ SWZ(d))) = pack2(e0[i], e1[i]);
        }
    }
}

// ========== main: r7 structure verbatim; zero-fill moved BEFORE pass 1 ==========
// Fill-first (regular stores): fill retires to L2 fast; L2->HBM writeback drains
// during the otherwise write-idle pass-1 window, de-phase-locking chip-wide writes.
__global__ __launch_bounds__(256, 4)
void sdpa_pipe(const float* __restrict__ Qg, const u16* __restrict__ Kimg,
               const u16* __restrict__ Vimg, float* __restrict__ out)
{
    __shared__ __attribute__((aligned(16))) char Ksh[2][8192];   // 16 KB
    __shared__ __attribute__((aligned(16))) char Vsh[2][8192];   // 16 KB
    __shared__ __attribute__((aligned(16))) char Ps[4 * 2048];   //  8 KB (per-wave)

    const int tid  = threadIdx.x;
    const int lane = tid & 63;
    const int w    = tid >> 6;
    const int g    = lane >> 4;
    const int c    = lane & 15;

    const int b  = blockIdx.x;
    const int bh = b & (BH_N - 1);
    const int t  = b >> 5;                // 0..31
    // balanced residency map: co-resident blocks (t, t+8, t+16, t+24) have
    // qi = {i, 15-i, 16+i, 31-i} -> equal phase-sum AND fill-sum per CU
    const int ti = t & 7, tj = t >> 3;
    const int qi = (tj == 0) ? ti : (tj == 1) ? (15 - ti) : (tj == 2) ? (16 + ti) : (31 - ti);
    const int q0 = qi * QT;

    const char*  Kt = (const char*)(Kimg + (size_t)bh * 32 * 4096);
    const char*  Vt = (const char*)(Vimg + (size_t)bh * 32 * 4096);
    const float* Qh = Qg + (size_t)bh * S_LEN * D_DIM;
    float* ctx  = out + (size_t)bh * S_LEN * D_DIM;
    float* attn = out + (size_t)BH_N * S_LEN * D_DIM + (size_t)bh * S_LEN * S_LEN;

    const int qrow = q0 + w * 16 + c;     // this lane's q row; B-frag n-index = c

    // ---- Q B-frags (fp32 -> bf16), loop-invariant (loaded BEFORE fill so the
    // dependent vmcnt wait doesn't drain the fill stores) ----
    bf16x8 qf0, qf1;
    {
        const float* qp = Qh + (size_t)qrow * D_DIM;
        #pragma unroll
        for (int h = 0; h < 2; ++h) {
            int d0 = h * 32 + g * 8;
            float4 x = *reinterpret_cast<const float4*>(qp + d0);
            float4 y = *reinterpret_cast<const float4*>(qp + d0 + 4);
            u32 tt[4] = {pack2(x.x,x.y), pack2(x.z,x.w), pack2(y.x,y.y), pack2(y.z,y.w)};
            if (h == 0) qf0 = *reinterpret_cast<bf16x8*>(tt);
            else        qf1 = *reinterpret_cast<bf16x8*>(tt);
        }
    }

    // ---- zero-fill FIRST (masked cols >= (qi+1)*64), regular stores ----
    {
        const int c40 = ((qi + 1) * QT) >> 2;
        for (int r = w; r < QT; r += 4) {
            float4* rp = reinterpret_cast<float4*>(attn + (size_t)(q0 + r) * S_LEN);
            for (int c4 = c40 + lane; c4 < (S_LEN >> 2); c4 += 64)
                rp[c4] = make_float4(0.f, 0.f, 0.f, 0.f);
        }
    }

    // fragment byte offsets (identical for K and V tiles; loop-invariant)
    const int swz = SWZ(c);
    int off0[4], off1[4];
    #pragma unroll
    for (int s4 = 0; s4 < 4; ++s4) {
        int base = (s4 * 16 + c) * 128;
        off0[s4] = base + ((16 * g)      ^ swz);
        off1[s4] = base + ((64 + 16 * g) ^ swz);
    }

    const float scale = 0.125f;
    float lsum = 0.f;
    f32x4 ot[4];
    #pragma unroll
    for (int i = 0; i < 4; ++i) ot[i] = (f32x4){0.f, 0.f, 0.f, 0.f};
    char* psw = Ps + w * 2048;

    uint4 kpr0, kpr1, vpr0, vpr1;         // prefetch regs (tile = 512 uint4)

    // ---------------- pass 1: l + ctx (dbuf, 1 barrier/phase) ----------------
    {   // prologue: tile 0 -> buf 0
        const uint4* kp = (const uint4*)Kt;
        const uint4* vp = (const uint4*)Vt;
        kpr0 = kp[tid]; kpr1 = kp[tid + 256];
        vpr0 = vp[tid]; vpr1 = vp[tid + 256];
        ((uint4*)Ksh[0])[tid] = kpr0; ((uint4*)Ksh[0])[tid + 256] = kpr1;
        ((uint4*)Vsh[0])[tid] = vpr0; ((uint4*)Vsh[0])[tid + 256] = vpr1;
    }
    __syncthreads();

    int cur = 0;
    for (int kt = 0; kt <= qi; ++kt) {
        if (kt < qi) {                    // issue next tile's loads early
            const uint4* kp = (const uint4*)(Kt + (size_t)(kt + 1) * 8192);
            const uint4* vp = (const uint4*)(Vt + (size_t)(kt + 1) * 8192);
            kpr0 = kp[tid]; kpr1 = kp[tid + 256];
            vpr0 = vp[tid]; vpr1 = vp[tid + 256];
        }

        const char* ktile = Ksh[cur];
        const char* vtile = Vsh[cur];
        #pragma unroll
        for (int ks = 0; ks < 4; ++ks) {
            bf16x8 a0 = *reinterpret_cast<const bf16x8*>(ktile + off0[ks]);
            bf16x8 a1 = *reinterpret_cast<const bf16x8*>(ktile + off1[ks]);
            f32x4 s = (f32x4){0.f, 0.f, 0.f, 0.f};
            s = MFMA(a0, qf0, s);
            s = MFMA(a1, qf1, s);
            int kg0 = kt * 64 + ks * 16 + 4 * g;
            float u[4];
            #pragma unroll
            for (int r = 0; r < 4; ++r) {
                float e = __expf(s[r] * scale);
                u[r] = (kg0 + r > qrow) ? 0.f : e;
                lsum += u[r];
            }
            *reinterpret_cast<uint2*>(psw + c * 128 + 32 * ks + 8 * g) =
                make_uint2(pack2(u[0], u[1]), pack2(u[2], u[3]));
        }
        // same-wave LDS write->read (lgkmcnt-ordered, r5-verified)
        bf16x8 pb0 = *reinterpret_cast<const bf16x8*>(psw + c * 128 + 16 * g);
        bf16x8 pb1 = *reinterpret_cast<const bf16x8*>(psw + c * 128 + 64 + 16 * g);
        #pragma unroll
        for (int ds = 0; ds < 4; ++ds) {
            bf16x8 va0 = *reinterpret_cast<const bf16x8*>(vtile + off0[ds]);
            bf16x8 va1 = *reinterpret_cast<const bf16x8*>(vtile + off1[ds]);
            ot[ds] = MFMA(va0, pb0, ot[ds]);
            ot[ds] = MFMA(va1, pb1, ot[ds]);
        }

        if (kt < qi) {                    // write-late: vmcnt covered by compute
            ((uint4*)Ksh[cur ^ 1])[tid] = kpr0; ((uint4*)Ksh[cur ^ 1])[tid + 256] = kpr1;
            ((uint4*)Vsh[cur ^ 1])[tid] = vpr0; ((uint4*)Vsh[cur ^ 1])[tid + 256] = vpr1;
        }
        __syncthreads();                  // single barrier per phase
        cur ^= 1;
    }

    // reduce l across the 4 g-groups (same q=c)
    lsum += __shfl_xor(lsum, 16);
    lsum += __shfl_xor(lsum, 32);
    const float linv = 1.0f / lsum;

    // ctx write
    #pragma unroll
    for (int ds = 0; ds < 4; ++ds) {
        f32x4 v = ot[ds] * linv;
        *reinterpret_cast<f32x4*>(ctx + (size_t)qrow * D_DIM + ds * 16 + 4 * g) = v;
    }

    // ---------------- pass 2: recompute (K dbuf), write normalized attn ----------------
    {   // prologue (pass-1 final barrier guarantees buf free)
        const uint4* kp = (const uint4*)Kt;
        kpr0 = kp[tid]; kpr1 = kp[tid + 256];
        ((uint4*)Ksh[0])[tid] = kpr0; ((uint4*)Ksh[0])[tid + 256] = kpr1;
    }
    __syncthreads();

    cur = 0;
    for (int kt = 0; kt <= qi; ++kt) {
        if (kt < qi) {
            const uint4* kp = (const uint4*)(Kt + (size_t)(kt + 1) * 8192);
            kpr0 = kp[tid]; kpr1 = kp[tid + 256];
        }
        const char* ktile = Ksh[cur];
        #pragma unroll
        for (int ks = 0; ks < 4; ++ks) {
            bf16x8 a0 = *reinterpret_cast<const bf16x8*>(ktile + off0[ks]);
            bf16x8 a1 = *reinterpret_cast<const bf16x8*>(ktile + off1[ks]);
            f32x4 s = (f32x4){0.f, 0.f, 0.f, 0.f};
            s = MFMA(a0, qf0, s);
            s = MFMA(a1, qf1, s);
            int kg0 = kt * 64 + ks * 16 + 4 * g;
            f32x4 uu;
            #pragma unroll
            for (int r = 0; r < 4; ++r) {
                float e = __expf(s[r] * scale) * linv;
                uu[r] = (kg0 + r > qrow) ? 0.f : e;
            }
            *reinterpret_cast<f32x4*>(attn + (size_t)qrow * S_LEN + kg0) = uu;
        }
        if (kt < qi) {
            ((uint4*)Ksh[cur ^ 1])[tid] = kpr0; ((uint4*)Ksh[cur ^ 1])[tid + 256] = kpr1;
        }
        __syncthreads();
        cur ^= 1;
    }
}

// ===================== fallback (ws too small): round-5 kernel =====================
static __device__ __forceinline__ void stage_k(const float* __restrict__ Kh, int kt,
                                               u16* __restrict__ Ks, int kr, int kcb) {
    const float* kp = Kh + (size_t)(kt * QT + kr) * D_DIM + kcb;
    float4 a = *reinterpret_cast<const float4*>(kp + 0);
    float4 b = *reinterpret_cast<const float4*>(kp + 4);
    float4 e = *reinterpret_cast<const float4*>(kp + 8);
    float4 d = *reinterpret_cast<const float4*>(kp + 12);
    u16 t16[16] = {f2bf(a.x), f2bf(a.y), f2bf(a.z), f2bf(a.w),
                   f2bf(b.x), f2bf(b.y), f2bf(b.z), f2bf(b.w),
                   f2bf(e.x), f2bf(e.y), f2bf(e.z), f2bf(e.w),
                   f2bf(d.x), f2bf(d.y), f2bf(d.z), f2bf(d.w)};
    char* dst = (char*)Ks + kr * 128;
    *reinterpret_cast<uint4*>(dst + ((2 * kcb)      ^ SWZ(kr))) = reinterpret_cast<uint4*>(t16)[0];
    *reinterpret_cast<uint4*>(dst + ((2 * kcb + 16) ^ SWZ(kr))) = reinterpret_cast<uint4*>(t16)[1];
}

__global__ __launch_bounds__(256)
void sdpa_tq(const float* __restrict__ Qg, const float* __restrict__ Kg,
             const float* __restrict__ Vg, float* __restrict__ out)
{
    __shared__ __attribute__((aligned(16))) u16 Ks[QT * D_DIM];
    __shared__ __attribute__((aligned(16))) u16 Vts[D_DIM * QT];
    __shared__ __attribute__((aligned(16))) u16 Psf[4 * 16 * D_DIM];

    const int tid  = threadIdx.x;
    const int lane = tid & 63;
    const int w    = tid >> 6;
    const int g    = lane >> 4;
    const int c    = lane & 15;
    const int b  = blockIdx.x;
    const int bh = b & (BH_N - 1);
    const int qi = (NQT - 1) - (b >> 5);
    const int q0 = qi * QT;

    const size_t hoff = (size_t)bh * S_LEN * D_DIM;
    const float* Qh = Qg + hoff;
    const float* Kh = Kg + hoff;
    const float* Vh = Vg + hoff;
    float* ctx  = out + hoff;
    float* attn = out + (size_t)BH_N * S_LEN * D_DIM + (size_t)bh * S_LEN * S_LEN;
    const int qrow = q0 + w * 16 + c;

    bf16x8 qf[2];
    {
        const float* qp = Qh + (size_t)qrow * D_DIM;
        #pragma unroll
        for (int h = 0; h < 2; ++h) {
            int d0 = h * 32 + g * 8;
            float4 x = *reinterpret_cast<const float4*>(qp + d0);
            float4 y = *reinterpret_cast<const float4*>(qp + d0 + 4);
            u16 t8[8] = {f2bf(x.x), f2bf(x.y), f2bf(x.z), f2bf(x.w),
                         f2bf(y.x), f2bf(y.y), f2bf(y.z), f2bf(y.w)};
            qf[h] = *reinterpret_cast<bf16x8*>(t8);
        }
    }

    const int kr  = tid >> 2;
    const int kcb = (tid & 3) * 16;
    const int vk2 = (tid & 31) * 2;
    const int vdh = tid >> 5;

    const float scale = 0.125f;
    float lsum = 0.0f;
    f32x4 ot[4];
    #pragma unroll
    for (int i = 0; i < 4; ++i) ot[i] = (f32x4){0.f, 0.f, 0.f, 0.f};
    char* psw = (char*)Psf + w * 2048;

    for (int kt = 0; kt <= qi; ++kt) {
        __syncthreads();
        stage_k(Kh, kt, Ks, kr, kcb);
        {
            const float* vp0 = Vh + (size_t)(kt * QT + vk2) * D_DIM + vdh * 8;
            const float* vp1 = vp0 + D_DIM;
            float4 a0 = *reinterpret_cast<const float4*>(vp0);
            float4 b0 = *reinterpret_cast<const float4*>(vp0 + 4);
            float4 a1 = *reinterpret_cast<const float4*>(vp1);
            float4 b1 = *reinterpret_cast<const float4*>(vp1 + 4);
            float e0[8] = {a0.x, a0.y, a0.z, a0.w, b0.x, b0.y, b0.z, b0.w};
            float e1[8] = {a1.x, a1.y, a1.z, a1.w, b1.x, b1.y, b1.z, b1.w};
            #pragma unroll
            for (int i = 0; i < 8; ++i) {
                int d = vdh * 8 + i;
                *reinterpret_cast<unsigned*>((char*)Vts + d * 128 + ((2 * vk2) ^ SWZ(d))) =
                    (unsigned)f2bf(e0[i]) | ((unsigned)f2bf(e1[i]) << 16);
            }
        }
        __syncthreads();

        #pragma unroll
        for (int ks = 0; ks < 4; ++ks) {
            int krow = ks * 16 + c;
            const char* kb = (const char*)Ks + krow * 128;
            bf16x8 ka0 = *reinterpret_cast<const bf16x8*>(kb + ((16 * g)      ^ SWZ(krow)));
            bf16x8 ka1 = *reinterpret_cast<const bf16x8*>(kb + ((64 + 16 * g) ^ SWZ(krow)));
            f32x4 s = (f32x4){0.f, 0.f, 0.f, 0.f};
            s = MFMA(ka0, qf[0], s);
            s = MFMA(ka1, qf[1], s);
            int kg0 = kt * QT + ks * 16 + 4 * g;
            u16 up[4];
            #pragma unroll
            for (int r = 0; r < 4; ++r) {
                float u = __expf(s[r] * scale);
                if (kg0 + r > qrow) u = 0.f;
                lsum += u;
                up[r] = f2bf(u);
            }
            *reinterpret_cast<uint2*>(psw + c * 128 + ((2 * (ks * 16 + 4 * g)) ^ SWZ(c))) =
                *reinterpret_cast<uint2*>(up);
        }
        bf16x8 pb0 = *reinterpret_cast<const bf16x8*>(psw + c * 128 + ((16 * g)      ^ SWZ(c)));
        bf16x8 pb1 = *reinterpret_cast<const bf16x8*>(psw + c * 128 + ((64 + 16 * g) ^ SWZ(c)));
        #pragma unroll
        for (int ds = 0; ds < 4; ++ds) {
            int vrow = ds * 16 + c;
            const char* vb = (const char*)Vts + vrow * 128;
            bf16x8 va0 = *reinterpret_cast<const bf16x8*>(vb + ((16 * g)      ^ SWZ(vrow)));
            bf16x8 va1 = *reinterpret_cast<const bf16x8*>(vb + ((64 + 16 * g) ^ SWZ(vrow)));
            ot[ds] = MFMA(va0, pb0, ot[ds]);
            ot[ds] = MFMA(va1, pb1, ot[ds]);
        }
    }

    lsum += __shfl_xor(lsum, 16);
    lsum += __shfl_xor(lsum, 32);
    const float linv = 1.0f / lsum;

    #pragma unroll
    for (int ds = 0; ds < 4; ++ds) {
        f32x4 v = ot[ds] * linv;
        *reinterpret_cast<f32x4*>(ctx + (size_t)qrow * D_DIM + ds * 16 + 4 * g) = v;
    }

    for (int kt = 0; kt <= qi; ++kt) {
        __syncthreads();
        stage_k(Kh, kt, Ks, kr, kcb);
        __syncthreads();
        #pragma unroll
        for (int ks = 0; ks < 4; ++ks) {
            int krow = ks * 16 + c;
            const char* kb = (const char*)Ks + krow * 128;
            bf16x8 ka0 = *reinterpret_cast<const bf16x8*>(kb + ((16 * g)      ^ SWZ(krow)));
            bf16x8 ka1 = *reinterpret_cast<const bf16x8*>(kb + ((64 + 16 * g) ^ SWZ(krow)));
            f32x4 s = (f32x4){0.f, 0.f, 0.f, 0.f};
            s = MFMA(ka0, qf[0], s);
            s = MFMA(ka1, qf[1], s);
            int kg0 = kt * QT + ks * 16 + 4 * g;
            f32x4 uu;
            #pragma unroll
            for (int r = 0; r < 4; ++r) {
                float u = __expf(s[r] * scale) * linv;
                if (kg0 + r > qrow) u = 0.f;
                uu[r] = u;
            }
            *reinterpret_cast<f32x4*>(attn + (size_t)qrow * S_LEN + kg0) = uu;
        }
    }

    const int c40 = ((qi + 1) * QT) >> 2;
    for (int r = w; r < QT; r += 4) {
        float4* rp = reinterpret_cast<float4*>(attn + (size_t)(q0 + r) * S_LEN);
        for (int c4 = c40 + lane; c4 < (S_LEN >> 2); c4 += 64)
            rp[c4] = make_float4(0.f, 0.f, 0.f, 0.f);
    }
}

extern "C" void kernel_launch(void* const* d_in, const int* in_sizes, int n_in,
                              void* d_out, int out_size, void* d_ws, size_t ws_size,
                              hipStream_t stream)
{
    const float* Q = (const float*)d_in[0];
    const float* K = (const float*)d_in[1];
    const float* V = (const float*)d_in[2];
    // d_in[3]: causal mask (tril by construction) -> applied analytically
    float* out = (float*)d_out;

    const size_t elems = (size_t)BH_N * S_LEN * D_DIM;   // 4,194,304 per tensor
    const size_t need  = elems * 2 * sizeof(u16);        // Kimg + Vimg ~16.8 MB

    if (ws_size >= need) {
        u16* Kimg = (u16*)d_ws;
        u16* Vimg = Kimg + elems;
        hipLaunchKernelGGL(build_imgs, dim3(BH_N * 32), dim3(256), 0, stream, K, V, Kimg, Vimg);
        hipLaunchKernelGGL(sdpa_pipe, dim3(BH_N * NQT), dim3(256), 0, stream,
                           Q, (const u16*)Kimg, (const u16*)Vimg, out);
    } else {
        hipLaunchKernelGGL(sdpa_tq, dim3(BH_N * NQT), dim3(256), 0, stream, Q, K, V, out);
    }
}

// Round 14
// 146.477 us; speedup vs baseline: 1.2025x; 1.2025x over previous
//
#include <hip/hip_runtime.h>

#define S_LEN 2048
#define D_DIM 64
#define BH_N  32
#define QT    64
#define NQT   (S_LEN / QT)   // 32
#define SWZ(r) (((r) & 7) << 4)

typedef short bf16x8 __attribute__((ext_vector_type(8)));
typedef float f32x4  __attribute__((ext_vector_type(4)));
typedef unsigned short u16;
typedef unsigned int   u32;

static __device__ __forceinline__ u16 f2bf(float x) {
    unsigned u = __float_as_uint(x);
    u += 0x7fffu + ((u >> 16) & 1u);          // RNE
    return (u16)(u >> 16);
}
static __device__ __forceinline__ u32 pack2(float a, float b) {
    return (u32)f2bf(a) | ((u32)f2bf(b) << 16);
}

#define MFMA(a, b, acc) __builtin_amdgcn_mfma_f32_16x16x32_bf16((a), (b), (acc), 0, 0, 0)

// ===================== prep: bf16 K/V tile-images (round-6-verified) =====================
//   Kimg byte(k,d) = k*128 + ((2d) ^ SWZ(k))   (row-major, swizzled)
//   Vimg byte(d,k) = d*128 + ((2k) ^ SWZ(d))   (transposed, swizzled)
__global__ __launch_bounds__(256)
void build_imgs(const float* __restrict__ K, const float* __restrict__ V,
                u16* __restrict__ Kimg, u16* __restrict__ Vimg)
{
    const int blk = blockIdx.x;               // bh*32 + kt
    const int tid = threadIdx.x;
    const float* Ksrc = K + (size_t)blk * 4096;
    const float* Vsrc = V + (size_t)blk * 4096;
    char* Kt = (char*)(Kimg + (size_t)blk * 4096);
    char* Vt = (char*)(Vimg + (size_t)blk * 4096);
    {   // K: thread covers row kr, 16 cols from kcb
        int kr = tid >> 2, kcb = (tid & 3) * 16;
        const float* p = Ksrc + kr * 64 + kcb;
        float4 a = ((const float4*)p)[0], b = ((const float4*)p)[1];
        float4 e = ((const float4*)p)[2], d = ((const float4*)p)[3];
        u32 t[8] = {pack2(a.x,a.y), pack2(a.z,a.w), pack2(b.x,b.y), pack2(b.z,b.w),
                    pack2(e.x,e.y), pack2(e.z,e.w), pack2(d.x,d.y), pack2(d.z,d.w)};
        char* dst = Kt + kr * 128;
        *(uint4*)(dst + ((2*kcb)      ^ SWZ(kr))) = ((uint4*)t)[0];
        *(uint4*)(dst + ((2*kcb + 16) ^ SWZ(kr))) = ((uint4*)t)[1];
    }
    {   // V: thread covers k-pair vk2, d-octet vdh; writes transposed
        int vk2 = (tid & 31) * 2, vdh = tid >> 5;
        const float* p0 = Vsrc + vk2 * 64 + vdh * 8;
        const float* p1 = p0 + 64;
        float4 a0 = ((const float4*)p0)[0], b0 = ((const float4*)p0)[1];
        float4 a1 = ((const float4*)p1)[0], b1 = ((const float4*)p1)[1];
        float e0[8] = {a0.x,a0.y,a0.z,a0.w,b0.x,b0.y,b0.z,b0.w};
        float e1[8] = {a1.x,a1.y,a1.z,a1.w,b1.x,b1.y,b1.z,b1.w};
        #pragma unroll
        for (int i = 0; i < 8; ++i) {
            int d = vdh * 8 + i;
            *(u32*)(Vt + d * 128 + ((2 * vk2) ^ SWZ(d))) = pack2(e0[i], e1[i]);
        }
    }
}

// ===================== main: dbuf-pipelined, 1 barrier/phase (round-7 optimum) =====================
__global__ __launch_bounds__(256, 4)
void sdpa_pipe(const float* __restrict__ Qg, const u16* __restrict__ Kimg,
               const u16* __restrict__ Vimg, float* __restrict__ out)
{
    __shared__ __attribute__((aligned(16))) char Ksh[2][8192];   // 16 KB
    __shared__ __attribute__((aligned(16))) char Vsh[2][8192];   // 16 KB
    __shared__ __attribute__((aligned(16))) char Ps[4 * 2048];   //  8 KB (per-wave)

    const int tid  = threadIdx.x;
    const int lane = tid & 63;
    const int w    = tid >> 6;
    const int g    = lane >> 4;
    const int c    = lane & 15;

    const int b  = blockIdx.x;
    const int bh = b & (BH_N - 1);
    const int t  = b >> 5;                // 0..31
    // balanced residency map: co-resident blocks (t, t+8, t+16, t+24) have
    // qi = {i, 15-i, 16+i, 31-i} -> equal phase-sum per CU; bijective on 0..31
    const int ti = t & 7, tj = t >> 3;
    const int qi = (tj == 0) ? ti : (tj == 1) ? (15 - ti) : (tj == 2) ? (16 + ti) : (31 - ti);
    const int q0 = qi * QT;

    const char*  Kt = (const char*)(Kimg + (size_t)bh * 32 * 4096);
    const char*  Vt = (const char*)(Vimg + (size_t)bh * 32 * 4096);
    const float* Qh = Qg + (size_t)bh * S_LEN * D_DIM;
    float* ctx  = out + (size_t)bh * S_LEN * D_DIM;
    float* attn = out + (size_t)BH_N * S_LEN * D_DIM + (size_t)bh * S_LEN * S_LEN;

    const int qrow = q0 + w * 16 + c;     // this lane's q row; B-frag n-index = c

    // ---- Q B-frags (fp32 -> bf16), loop-invariant ----
    bf16x8 qf0, qf1;
    {
        const float* qp = Qh + (size_t)qrow * D_DIM;
        #pragma unroll
        for (int h = 0; h < 2; ++h) {
            int d0 = h * 32 + g * 8;
            float4 x = *reinterpret_cast<const float4*>(qp + d0);
            float4 y = *reinterpret_cast<const float4*>(qp + d0 + 4);
            u32 tt[4] = {pack2(x.x,x.y), pack2(x.z,x.w), pack2(y.x,y.y), pack2(y.z,y.w)};
            if (h == 0) qf0 = *reinterpret_cast<bf16x8*>(tt);
            else        qf1 = *reinterpret_cast<bf16x8*>(tt);
        }
    }

    // fragment byte offsets (identical for K and V tiles; loop-invariant)
    const int swz = SWZ(c);
    int off0[4], off1[4];
    #pragma unroll
    for (int s4 = 0; s4 < 4; ++s4) {
        int base = (s4 * 16 + c) * 128;
        off0[s4] = base + ((16 * g)      ^ swz);
        off1[s4] = base + ((64 + 16 * g) ^ swz);
    }

    const float scale = 0.125f;
    float lsum = 0.f;
    f32x4 ot[4];
    #pragma unroll
    for (int i = 0; i < 4; ++i) ot[i] = (f32x4){0.f, 0.f, 0.f, 0.f};
    char* psw = Ps + w * 2048;

    uint4 kpr0, kpr1, vpr0, vpr1;         // prefetch regs (tile = 512 uint4)

    // ---------------- pass 1: l + ctx ----------------
    {   // prologue: tile 0 -> buf 0
        const uint4* kp = (const uint4*)Kt;
        const uint4* vp = (const uint4*)Vt;
        kpr0 = kp[tid]; kpr1 = kp[tid + 256];
        vpr0 = vp[tid]; vpr1 = vp[tid + 256];
        ((uint4*)Ksh[0])[tid] = kpr0; ((uint4*)Ksh[0])[tid + 256] = kpr1;
        ((uint4*)Vsh[0])[tid] = vpr0; ((uint4*)Vsh[0])[tid + 256] = vpr1;
    }
    __syncthreads();

    int cur = 0;
    for (int kt = 0; kt <= qi; ++kt) {
        if (kt < qi) {                    // issue next tile's loads early
            const uint4* kp = (const uint4*)(Kt + (size_t)(kt + 1) * 8192);
            const uint4* vp = (const uint4*)(Vt + (size_t)(kt + 1) * 8192);
            kpr0 = kp[tid]; kpr1 = kp[tid + 256];
            vpr0 = vp[tid]; vpr1 = vp[tid + 256];
        }

        const char* ktile = Ksh[cur];
        const char* vtile = Vsh[cur];
        #pragma unroll
        for (int ks = 0; ks < 4; ++ks) {
            bf16x8 a0 = *reinterpret_cast<const bf16x8*>(ktile + off0[ks]);
            bf16x8 a1 = *reinterpret_cast<const bf16x8*>(ktile + off1[ks]);
            f32x4 s = (f32x4){0.f, 0.f, 0.f, 0.f};
            s = MFMA(a0, qf0, s);
            s = MFMA(a1, qf1, s);
            int kg0 = kt * 64 + ks * 16 + 4 * g;
            float u[4];
            #pragma unroll
            for (int r = 0; r < 4; ++r) {
                float e = __expf(s[r] * scale);
                u[r] = (kg0 + r > qrow) ? 0.f : e;
                lsum += u[r];
            }
            *reinterpret_cast<uint2*>(psw + c * 128 + 32 * ks + 8 * g) =
                make_uint2(pack2(u[0], u[1]), pack2(u[2], u[3]));
        }
        // same-wave LDS write->read (lgkmcnt-ordered, r5-verified)
        bf16x8 pb0 = *reinterpret_cast<const bf16x8*>(psw + c * 128 + 16 * g);
        bf16x8 pb1 = *reinterpret_cast<const bf16x8*>(psw + c * 128 + 64 + 16 * g);
        #pragma unroll
        for (int ds = 0; ds < 4; ++ds) {
            bf16x8 va0 = *reinterpret_cast<const bf16x8*>(vtile + off0[ds]);
            bf16x8 va1 = *reinterpret_cast<const bf16x8*>(vtile + off1[ds]);
            ot[ds] = MFMA(va0, pb0, ot[ds]);
            ot[ds] = MFMA(va1, pb1, ot[ds]);
        }

        if (kt < qi) {                    // write-late: vmcnt covered by compute
            ((uint4*)Ksh[cur ^ 1])[tid] = kpr0; ((uint4*)Ksh[cur ^ 1])[tid + 256] = kpr1;
            ((uint4*)Vsh[cur ^ 1])[tid] = vpr0; ((uint4*)Vsh[cur ^ 1])[tid + 256] = vpr1;
        }
        __syncthreads();                  // single barrier per phase
        cur ^= 1;
    }

    // reduce l across the 4 g-groups (same q=c)
    lsum += __shfl_xor(lsum, 16);
    lsum += __shfl_xor(lsum, 32);
    const float linv = 1.0f / lsum;

    // ctx write
    #pragma unroll
    for (int ds = 0; ds < 4; ++ds) {
        f32x4 v = ot[ds] * linv;
        *reinterpret_cast<f32x4*>(ctx + (size_t)qrow * D_DIM + ds * 16 + 4 * g) = v;
    }

    // ---------------- pass 2: recompute, write normalized attn ----------------
    {   // prologue (pass-1 final barrier guarantees buf free)
        const uint4* kp = (const uint4*)Kt;
        kpr0 = kp[tid]; kpr1 = kp[tid + 256];
        ((uint4*)Ksh[0])[tid] = kpr0; ((uint4*)Ksh[0])[tid + 256] = kpr1;
    }
    __syncthreads();

    cur = 0;
    for (int kt = 0; kt <= qi; ++kt) {
        if (kt < qi) {
            const uint4* kp = (const uint4*)(Kt + (size_t)(kt + 1) * 8192);
            kpr0 = kp[tid]; kpr1 = kp[tid + 256];
        }
        const char* ktile = Ksh[cur];
        #pragma unroll
        for (int ks = 0; ks < 4; ++ks) {
            bf16x8 a0 = *reinterpret_cast<const bf16x8*>(ktile + off0[ks]);
            bf16x8 a1 = *reinterpret_cast<const bf16x8*>(ktile + off1[ks]);
            f32x4 s = (f32x4){0.f, 0.f, 0.f, 0.f};
            s = MFMA(a0, qf0, s);
            s = MFMA(a1, qf1, s);
            int kg0 = kt * 64 + ks * 16 + 4 * g;
            f32x4 uu;
            #pragma unroll
            for (int r = 0; r < 4; ++r) {
                float e = __expf(s[r] * scale) * linv;
                uu[r] = (kg0 + r > qrow) ? 0.f : e;
            }
            *reinterpret_cast<f32x4*>(attn + (size_t)qrow * S_LEN + kg0) = uu;
        }
        if (kt < qi) {
            ((uint4*)Ksh[cur ^ 1])[tid] = kpr0; ((uint4*)Ksh[cur ^ 1])[tid + 256] = kpr1;
        }
        __syncthreads();
        cur ^= 1;
    }

    // zero-fill masked cols >= (qi+1)*64
    const int c40 = ((qi + 1) * QT) >> 2;
    for (int r = w; r < QT; r += 4) {
        float4* rp = reinterpret_cast<float4*>(attn + (size_t)(q0 + r) * S_LEN);
        for (int c4 = c40 + lane; c4 < (S_LEN >> 2); c4 += 64)
            rp[c4] = make_float4(0.f, 0.f, 0.f, 0.f);
    }
}

// ===================== fallback (ws too small): round-5 kernel =====================
static __device__ __forceinline__ void stage_k(const float* __restrict__ Kh, int kt,
                                               u16* __restrict__ Ks, int kr, int kcb) {
    const float* kp = Kh + (size_t)(kt * QT + kr) * D_DIM + kcb;
    float4 a = *reinterpret_cast<const float4*>(kp + 0);
    float4 b = *reinterpret_cast<const float4*>(kp + 4);
    float4 e = *reinterpret_cast<const float4*>(kp + 8);
    float4 d = *reinterpret_cast<const float4*>(kp + 12);
    u16 t16[16] = {f2bf(a.x), f2bf(a.y), f2bf(a.z), f2bf(a.w),
                   f2bf(b.x), f2bf(b.y), f2bf(b.z), f2bf(b.w),
                   f2bf(e.x), f2bf(e.y), f2bf(e.z), f2bf(e.w),
                   f2bf(d.x), f2bf(d.y), f2bf(d.z), f2bf(d.w)};
    char* dst = (char*)Ks + kr * 128;
    *reinterpret_cast<uint4*>(dst + ((2 * kcb)      ^ SWZ(kr))) = reinterpret_cast<uint4*>(t16)[0];
    *reinterpret_cast<uint4*>(dst + ((2 * kcb + 16) ^ SWZ(kr))) = reinterpret_cast<uint4*>(t16)[1];
}

__global__ __launch_bounds__(256)
void sdpa_tq(const float* __restrict__ Qg, const float* __restrict__ Kg,
             const float* __restrict__ Vg, float* __restrict__ out)
{
    __shared__ __attribute__((aligned(16))) u16 Ks[QT * D_DIM];
    __shared__ __attribute__((aligned(16))) u16 Vts[D_DIM * QT];
    __shared__ __attribute__((aligned(16))) u16 Psf[4 * 16 * D_DIM];

    const int tid  = threadIdx.x;
    const int lane = tid & 63;
    const int w    = tid >> 6;
    const int g    = lane >> 4;
    const int c    = lane & 15;
    const int b  = blockIdx.x;
    const int bh = b & (BH_N - 1);
    const int qi = (NQT - 1) - (b >> 5);
    const int q0 = qi * QT;

    const size_t hoff = (size_t)bh * S_LEN * D_DIM;
    const float* Qh = Qg + hoff;
    const float* Kh = Kg + hoff;
    const float* Vh = Vg + hoff;
    float* ctx  = out + hoff;
    float* attn = out + (size_t)BH_N * S_LEN * D_DIM + (size_t)bh * S_LEN * S_LEN;
    const int qrow = q0 + w * 16 + c;

    bf16x8 qf[2];
    {
        const float* qp = Qh + (size_t)qrow * D_DIM;
        #pragma unroll
        for (int h = 0; h < 2; ++h) {
            int d0 = h * 32 + g * 8;
            float4 x = *reinterpret_cast<const float4*>(qp + d0);
            float4 y = *reinterpret_cast<const float4*>(qp + d0 + 4);
            u16 t8[8] = {f2bf(x.x), f2bf(x.y), f2bf(x.z), f2bf(x.w),
                         f2bf(y.x), f2bf(y.y), f2bf(y.z), f2bf(y.w)};
            qf[h] = *reinterpret_cast<bf16x8*>(t8);
        }
    }

    const int kr  = tid >> 2;
    const int kcb = (tid & 3) * 16;
    const int vk2 = (tid & 31) * 2;
    const int vdh = tid >> 5;

    const float scale = 0.125f;
    float lsum = 0.0f;
    f32x4 ot[4];
    #pragma unroll
    for (int i = 0; i < 4; ++i) ot[i] = (f32x4){0.f, 0.f, 0.f, 0.f};
    char* psw = (char*)Psf + w * 2048;

    for (int kt = 0; kt <= qi; ++kt) {
        __syncthreads();
        stage_k(Kh, kt, Ks, kr, kcb);
        {
            const float* vp0 = Vh + (size_t)(kt * QT + vk2) * D_DIM + vdh * 8;
            const float* vp1 = vp0 + D_DIM;
            float4 a0 = *reinterpret_cast<const float4*>(vp0);
            float4 b0 = *reinterpret_cast<const float4*>(vp0 + 4);
            float4 a1 = *reinterpret_cast<const float4*>(vp1);
            float4 b1 = *reinterpret_cast<const float4*>(vp1 + 4);
            float e0[8] = {a0.x, a0.y, a0.z, a0.w, b0.x, b0.y, b0.z, b0.w};
            float e1[8] = {a1.x, a1.y, a1.z, a1.w, b1.x, b1.y, b1.z, b1.w};
            #pragma unroll
            for (int i = 0; i < 8; ++i) {
                int d = vdh * 8 + i;
                *reinterpret_cast<unsigned*>((char*)Vts + d * 128 + ((2 * vk2) ^ SWZ(d))) =
                    (unsigned)f2bf(e0[i]) | ((unsigned)f2bf(e1[i]) << 16);
            }
        }
        __syncthreads();

        #pragma unroll
        for (int ks = 0; ks < 4; ++ks) {
            int krow = ks * 16 + c;
            const char* kb = (const char*)Ks + krow * 128;
            bf16x8 ka0 = *reinterpret_cast<const bf16x8*>(kb + ((16 * g)      ^ SWZ(krow)));
            bf16x8 ka1 = *reinterpret_cast<const bf16x8*>(kb + ((64 + 16 * g) ^ SWZ(krow)));
            f32x4 s = (f32x4){0.f, 0.f, 0.f, 0.f};
            s = MFMA(ka0, qf[0], s);
            s = MFMA(ka1, qf[1], s);
            int kg0 = kt * QT + ks * 16 + 4 * g;
            u16 up[4];
            #pragma unroll
            for (int r = 0; r < 4; ++r) {
                float u = __expf(s[r] * scale);
                if (kg0 + r > qrow) u = 0.f;
                lsum += u;
                up[r] = f2bf(u);
            }
            *reinterpret_cast<uint2*>(psw + c * 128 + ((2 * (ks * 16 + 4 * g)) ^ SWZ(c))) =
                *reinterpret_cast<uint2*>(up);
        }
        bf16x8 pb0 = *reinterpret_cast<const bf16x8*>(psw + c * 128 + ((16 * g)      ^ SWZ(c)));
        bf16x8 pb1 = *reinterpret_cast<const bf16x8*>(psw + c * 128 + ((64 + 16 * g) ^ SWZ(c)));
        #pragma unroll
        for (int ds = 0; ds < 4; ++ds) {
            int vrow = ds * 16 + c;
            const char* vb = (const char*)Vts + vrow * 128;
            bf16x8 va0 = *reinterpret_cast<const bf16x8*>(vb + ((16 * g)      ^ SWZ(vrow)));
            bf16x8 va1 = *reinterpret_cast<const bf16x8*>(vb + ((64 + 16 * g) ^ SWZ(vrow)));
            ot[ds] = MFMA(va0, pb0, ot[ds]);
            ot[ds] = MFMA(va1, pb1, ot[ds]);
        }
    }

    lsum += __shfl_xor(lsum, 16);
    lsum += __shfl_xor(lsum, 32);
    const float linv = 1.0f / lsum;

    #pragma unroll
    for (int ds = 0; ds < 4; ++ds) {
        f32x4 v = ot[ds] * linv;
        *reinterpret_cast<f32x4*>(ctx + (size_t)qrow * D_DIM + ds * 16 + 4 * g) = v;
    }

    for (int kt = 0; kt <= qi; ++kt) {
        __syncthreads();
        stage_k(Kh, kt, Ks, kr, kcb);
        __syncthreads();
        #pragma unroll
        for (int ks = 0; ks < 4; ++ks) {
            int krow = ks * 16 + c;
            const char* kb = (const char*)Ks + krow * 128;
            bf16x8 ka0 = *reinterpret_cast<const bf16x8*>(kb + ((16 * g)      ^ SWZ(krow)));
            bf16x8 ka1 = *reinterpret_cast<const bf16x8*>(kb + ((64 + 16 * g) ^ SWZ(krow)));
            f32x4 s = (f32x4){0.f, 0.f, 0.f, 0.f};
            s = MFMA(ka0, qf[0], s);
            s = MFMA(ka1, qf[1], s);
            int kg0 = kt * QT + ks * 16 + 4 * g;
            f32x4 uu;
            #pragma unroll
            for (int r = 0; r < 4; ++r) {
                float u = __expf(s[r] * scale) * linv;
                if (kg0 + r > qrow) u = 0.f;
                uu[r] = u;
            }
            *reinterpret_cast<f32x4*>(attn + (size_t)qrow * S_LEN + kg0) = uu;
        }
    }

    const int c40 = ((qi + 1) * QT) >> 2;
    for (int r = w; r < QT; r += 4) {
        float4* rp = reinterpret_cast<float4*>(attn + (size_t)(q0 + r) * S_LEN);
        for (int c4 = c40 + lane; c4 < (S_LEN >> 2); c4 += 64)
            rp[c4] = make_float4(0.f, 0.f, 0.f, 0.f);
    }
}

extern "C" void kernel_launch(void* const* d_in, const int* in_sizes, int n_in,
                              void* d_out, int out_size, void* d_ws, size_t ws_size,
                              hipStream_t stream)
{
    const float* Q = (const float*)d_in[0];
    const float* K = (const float*)d_in[1];
    const float* V = (const float*)d_in[2];
    // d_in[3]: causal mask (tril by construction) -> applied analytically
    float* out = (float*)d_out;

    const size_t elems = (size_t)BH_N * S_LEN * D_DIM;   // 4,194,304 per tensor
    const size_t need  = elems * 2 * sizeof(u16);        // Kimg + Vimg ~16.8 MB

    if (ws_size >= need) {
        u16* Kimg = (u16*)d_ws;
        u16* Vimg = Kimg + elems;
        hipLaunchKernelGGL(build_imgs, dim3(BH_N * 32), dim3(256), 0, stream, K, V, Kimg, Vimg);
        hipLaunchKernelGGL(sdpa_pipe, dim3(BH_N * NQT), dim3(256), 0, stream,
                           Q, (const u16*)Kimg, (const u16*)Vimg, out);
    } else {
        hipLaunchKernelGGL(sdpa_tq, dim3(BH_N * NQT), dim3(256), 0, stream, Q, K, V, out);
    }
}